// Round 13
// baseline (110.770 us; speedup 1.0000x reference)
//
#include <hip/hip_runtime.h>
#include <hip/hip_bf16.h>

// Problem constants: T=1024, B=2, E=1024, H=16, D=64, R=2*T-1
#define TT 1024
#define BB 2
#define EE 1024
#define HH 16
#define DD 64
#define RR 2047
#define TB (TT * BB)   // 2048
#define E3 (3 * EE)    // 3072

#define AS1 __attribute__((address_space(1)))
#define AS3 __attribute__((address_space(3)))

typedef __attribute__((ext_vector_type(4))) float f32x4;
typedef __attribute__((ext_vector_type(8))) short s16x8;

static __device__ __forceinline__ short f2bf(float x) {
  unsigned u = __builtin_bit_cast(unsigned, x);
  unsigned r = (u + 0x7FFFu + ((u >> 16) & 1u)) >> 16;
  return (short)r;
}
static __device__ __forceinline__ float bf2f(short x) {
  unsigned u = ((unsigned)(unsigned short)x) << 16;
  return __builtin_bit_cast(float, u);
}
static __device__ __forceinline__ float bperm(int idx, float v) {
  return __builtin_bit_cast(float,
      __builtin_amdgcn_ds_bpermute(idx, __builtin_bit_cast(int, v)));
}

// ---------------------------------------------------------------------------
// Fused fp32 -> bf16 convert for all 5 tensors (one launch).
// ---------------------------------------------------------------------------
__global__ __launch_bounds__(256) void cvt_all(
    const float* __restrict__ x, const float* __restrict__ in_w,
    const float* __restrict__ pos, const float* __restrict__ pos_w,
    const float* __restrict__ out_w,
    short* __restrict__ xb, short* __restrict__ inwb, short* __restrict__ posb,
    short* __restrict__ poswb, short* __restrict__ outwb) {
  const long M1 = 1 << 20;
  long off = (long)(blockIdx.x * 256 + threadIdx.x) * 8;
  const float* src; short* dst; long nsrc;
  if (off < 2 * M1)      { src = x;     dst = xb;    nsrc = 2 * M1; }
  else if (off < 5 * M1) { off -= 2 * M1; src = in_w;  dst = inwb;  nsrc = 3 * M1; }
  else if (off < 7 * M1) { off -= 5 * M1; src = pos;   dst = posb;  nsrc = (long)RR * EE; }
  else if (off < 8 * M1) { off -= 7 * M1; src = pos_w; dst = poswb; nsrc = M1; }
  else                   { off -= 8 * M1; src = out_w; dst = outwb; nsrc = M1; }
  s16x8 o;
  if (off + 8 <= nsrc) {
    f32x4 a = *(const f32x4*)&src[off];
    f32x4 c = *(const f32x4*)&src[off + 4];
    #pragma unroll
    for (int j = 0; j < 4; ++j) { o[j] = f2bf(a[j]); o[4 + j] = f2bf(c[j]); }
  } else {
    #pragma unroll
    for (int j = 0; j < 8; ++j) o[j] = 0;
  }
  *(s16x8*)&dst[off] = o;
}

// ---------------------------------------------------------------------------
// bf16 MFMA GEMM body (m97 structure), tile-parameterized.
//   C[M,N] = A[M,K] @ W[N,K]^T + bias[N]; 256 threads; waves WR x WC.
//   vtflag: write bf16 output in transposed vT[bh][d][key] layout instead
//   (cols are V-part cols in [2048,3072); row = token = key*2+b).
// ---------------------------------------------------------------------------
#define GBK 32

template <int BM, int BN, int WR, int WC, int OUT_BF16>
__device__ __forceinline__ void gemm_body(
    const short* __restrict__ A, const short* __restrict__ W,
    const float* __restrict__ bias, void* __restrict__ Cout,
    int M, int N, int K, int m0, int n0,
    short* __restrict__ vtout, int vtflag) {
  __shared__ __align__(16) short lA[2][BM * GBK];
  __shared__ __align__(16) short lB[2][BN * GBK];
  constexpr int MT = BM / WR / 16;
  constexpr int NT = BN / WC / 16;
  constexpr int ACH = BM * 4 / 256;
  constexpr int BCH = BN * 4 / 256;

  const int tid = threadIdx.x;
  const int lane = tid & 63;
  const int wv = tid >> 6;
  const int g = lane >> 4, cc = lane & 15;
  const int wr = wv / WC, wc = wv % WC;

  f32x4 acc[MT][NT];
  #pragma unroll
  for (int i = 0; i < MT; ++i)
    #pragma unroll
    for (int j = 0; j < NT; ++j) acc[i][j] = (f32x4){0.f, 0.f, 0.f, 0.f};

  auto stage = [&](int kk, int buf) {
    #pragma unroll
    for (int s = 0; s < ACH; ++s) {
      int c = s * 256 + tid;
      int row = c >> 2, slot = c & 3;
      int k8 = slot ^ (row & 3);
      __builtin_amdgcn_global_load_lds(
          (const AS1 void*)(A + (size_t)(m0 + row) * K + kk + k8 * 8),
          (AS3 void*)&lA[buf][c * 8], 16, 0, 0);
    }
    #pragma unroll
    for (int s = 0; s < BCH; ++s) {
      int c = s * 256 + tid;
      int row = c >> 2, slot = c & 3;
      int k8 = slot ^ (row & 3);
      __builtin_amdgcn_global_load_lds(
          (const AS1 void*)(W + (size_t)(n0 + row) * K + kk + k8 * 8),
          (AS3 void*)&lB[buf][c * 8], 16, 0, 0);
    }
  };

  int cur = 0;
  const int nt = K / GBK;
  stage(0, 0);

  #pragma unroll 1
  for (int t = 0; t < nt; ++t) {
    __syncthreads();
    if (t + 1 < nt) stage((t + 1) * GBK, cur ^ 1);

    s16x8 af[MT], bf[NT];
    #pragma unroll
    for (int mt = 0; mt < MT; ++mt) {
      int row = (BM / WR) * wr + 16 * mt + cc;
      af[mt] = *(const s16x8*)&lA[cur][row * GBK + ((g ^ (row & 3)) * 8)];
    }
    #pragma unroll
    for (int ntc = 0; ntc < NT; ++ntc) {
      int col = (BN / WC) * wc + 16 * ntc + cc;
      bf[ntc] = *(const s16x8*)&lB[cur][col * GBK + ((g ^ (col & 3)) * 8)];
    }
    #pragma unroll
    for (int mt = 0; mt < MT; ++mt)
      #pragma unroll
      for (int ntc = 0; ntc < NT; ++ntc)
        acc[mt][ntc] = __builtin_amdgcn_mfma_f32_16x16x32_bf16(
            af[mt], bf[ntc], acc[mt][ntc], 0, 0, 0);
    cur ^= 1;
  }

  #pragma unroll
  for (int ntc = 0; ntc < NT; ++ntc) {
    int col = n0 + (BN / WC) * wc + 16 * ntc + cc;
    float bv = bias[col];
    #pragma unroll
    for (int mt = 0; mt < MT; ++mt)
      #pragma unroll
      for (int r = 0; r < 4; ++r) {
        int rowg = m0 + (BM / WR) * wr + 16 * mt + 4 * g + r;
        float val = acc[mt][ntc][r] + bv;
        if (OUT_BF16) {
          if (vtflag) {
            // V-part: write transposed vT[(b*16+h)*64+d][key=i]
            const int cv = col - 2048;
            const int hh = cv >> 6, dd = cv & 63;
            vtout[((size_t)((rowg & 1) * 16 + hh) * 64 + dd) * TT + (rowg >> 1)] =
                f2bf(val);
          } else {
            ((short*)Cout)[(size_t)rowg * N + col] = f2bf(val);
          }
        } else {
          ((float*)Cout)[(size_t)rowg * N + col] = val;
        }
      }
  }
}

// Fused qkv-proj (384 blocks) + pos-proj (128 blocks); V-cols write vT direct.
__global__ __launch_bounds__(256) void gemm_qkv_pos(
    const short* __restrict__ xb, const short* __restrict__ inwb,
    const float* __restrict__ in_b, short* __restrict__ qkvb,
    const short* __restrict__ posb, const short* __restrict__ poswb,
    const float* __restrict__ pos_b, short* __restrict__ pb,
    short* __restrict__ vTb) {
  const int bid = blockIdx.x;
  const short *A, *W; const float* bias; short* C; int N, m0, n0, vtf;
  if (bid < 384) {                // qkv: [2048 x 3072 x 1024]
    A = xb; W = inwb; bias = in_b; C = qkvb; N = E3;
    n0 = (bid % 24) * 128; m0 = (bid / 24) * 128;
    vtf = (n0 >= 2048) ? 1 : 0;   // V columns -> vT layout
  } else {                        // pos: [2048 x 1024 x 1024]
    const int i = bid - 384;
    A = posb; W = poswb; bias = pos_b; C = pb; N = EE;
    n0 = (i % 8) * 128; m0 = (i / 8) * 128;
    vtf = 0;
  }
  gemm_body<128, 128, 2, 2, 1>(A, W, bias, C, TB, N, EE, m0, n0, vTb, vtf);
}

// out-proj: 128x64 tiles -> 256 blocks, fp32 out.
__global__ __launch_bounds__(256) void gemm_out(
    const short* __restrict__ ctxb, const short* __restrict__ outwb,
    const float* __restrict__ out_b, float* __restrict__ out) {
  gemm_body<128, 64, 4, 1, 0>(ctxb, outwb, out_b, out, TB, EE, EE,
                              blockIdx.y * 128, blockIdx.x * 64, nullptr, 0);
}

// ---------------------------------------------------------------------------
// MFMA flash attention — m97-style staged structure + rolling 3-panel P-ring.
//   512 blocks (XCD-bijective), 512 thr = 8 waves = (qsub 0..3) x (ksub 0..1).
//   Block owns 64 q-rows; 16 steps of 64 keys. Per step: K (8KB) + vT (8KB)
//   double-buffered, P staged as ring of three 64-row panels (8KB each) —
//   the band slides 64 rows/step so only ONE new panel per step (staging
//   24->16 KB/step, p fetch halved). Ring safety: panel n+2 overwrites the
//   slot of panel n-1, last read at step t-1, guarded by the step barrier.
//   Wave computes 16q x 32k: AC + BD (bperm gather) + exact defer-max
//   softmax + sPm roundtrip + PV.
// LDS (68608 B): K dbuf @0 (2x8K) | V dbuf @16384 (2x8K) | P ring @32768
//   (3x8K) | sPm @57344 (8x1280) | sML @67584 (1K).
//   Merge sO[w]=arena+w*4352 aliases staging (barrier-protected).
// ---------------------------------------------------------------------------
__global__ __launch_bounds__(512, 4) void rel_attn_mfma9(
    const short* __restrict__ qkvb,  // [TB][3E] bf16 (Q,K parts)
    const short* __restrict__ pb,    // [2048][E] bf16 (row 2047 zeroed)
    const short* __restrict__ vT,    // [BH][64][1024] bf16
    const float* __restrict__ rwb,   // [H*D]
    const float* __restrict__ rrb,   // [H*D]
    short* __restrict__ ctxb) {      // [TB][E] bf16
  __shared__ __align__(16) char arena[68608];

  const int tid = threadIdx.x;
  const int wv = tid >> 6;
  const int qsub = wv & 3, ksub = wv >> 2;
  const int lane = tid & 63;
  const int g = lane >> 4, cc = lane & 15;

  // XCD-bijective decode over 512 blocks: all 16 q-blocks of a bh on one XCD
  const int bid = blockIdx.x;
  const int bh = (bid & 7) * 4 + (bid >> 7);   // [0,32)
  const int qx = (bid >> 3) & 15;              // [0,16)
  const int iq0 = qx * 64;
  const int b = bh >> 4, h = bh & 15;
  const int hoff = h * DD;
  const int n0p = 15 - qx;                     // absolute panel idx at step 0

  short* sPm = (short*)(arena + 57344 + wv * 1280);    // [16][40]

  // ---- Q fragments: q row = iq0 + 16*qsub + cc ----
  s16x8 qw[2], qr[2];
  #pragma unroll
  for (int kh = 0; kh < 2; ++kh) {
    const int d0 = 32 * kh + 8 * g;
    const short* qp = qkvb + (size_t)((iq0 + 16 * qsub + cc) * BB + b) * E3 + hoff + d0;
    const float* rw = rwb + hoff + d0;
    const float* rr = rrb + hoff + d0;
    s16x8 qv = *(const s16x8*)qp;
    #pragma unroll
    for (int j = 0; j < 8; ++j) {
      float q = bf2f(qv[j]);
      qw[kh][j] = f2bf((q + rw[j]) * 0.125f);
      qr[kh][j] = f2bf((q + rr[j]) * 0.125f);
    }
  }

  f32x4 O[4];
  #pragma unroll
  for (int dt = 0; dt < 4; ++dt) O[dt] = (f32x4){0.f, 0.f, 0.f, 0.f};
  float mrun[4], lpart[4];
  #pragma unroll
  for (int r = 0; r < 4; ++r) { mrun[r] = -1e30f; lpart[r] = 0.f; }

  // K tile + V tile for step t_ into dbuf buf_
#define STAGE_KV(t_, buf_)                                                     \
  {                                                                            \
    const int j0s = (t_) * 64;                                                 \
    const int row = tid >> 3, c8 = tid & 7;                                    \
    const int swz = (c8 ^ (row & 7)) * 8;                                      \
    __builtin_amdgcn_global_load_lds(                                          \
        (const AS1 void*)(qkvb + (size_t)((j0s + row) * BB + b) * E3 + EE + hoff + swz), \
        (AS3 void*)(arena + (buf_) * 8192 + tid * 16), 16, 0, 0);              \
    __builtin_amdgcn_global_load_lds(                                          \
        (const AS1 void*)(vT + (size_t)(bh * DD + row) * TT + j0s + swz),      \
        (AS3 void*)(arena + 16384 + (buf_) * 8192 + tid * 16), 16, 0, 0);      \
  }
  // one 64-row p panel (absolute panel index p_) into ring slot p_%3
#define STAGE_P(p_)                                                            \
  {                                                                            \
    const int row = tid >> 3, c8 = tid & 7;                                    \
    const int swz = (c8 ^ (row & 7)) * 8;                                      \
    __builtin_amdgcn_global_load_lds(                                          \
        (const AS1 void*)(pb + (size_t)((p_) * 64 + row) * EE + hoff + swz),   \
        (AS3 void*)(arena + 32768 + ((p_) % 3) * 8192 + tid * 16), 16, 0, 0);  \
  }

  int cur = 0;
  int sl0 = n0p % 3, sl1 = (n0p + 1) % 3;
  STAGE_KV(0, 0);
  STAGE_P(n0p);
  STAGE_P(n0p + 1);

  #pragma unroll 1
  for (int t = 0; t < 16; ++t) {
    __syncthreads();   // stage(t) landed; buf[cur^1] + ring slot free
    if (t + 1 < 16) {
      STAGE_KV(t + 1, cur ^ 1);
      STAGE_P(n0p + t + 2);
    }

    short* ldsK = (short*)(arena + cur * 8192);           // [64 keys][64 d]
    short* ldsV = (short*)(arena + 16384 + cur * 8192);   // [64 d][64 keys]

    // ---- K fragments ----
    s16x8 kf[2][2];
    #pragma unroll
    for (int ct = 0; ct < 2; ++ct)
      #pragma unroll
      for (int kh = 0; kh < 2; ++kh) {
        const int row = 32 * ksub + 16 * ct + cc;
        kf[ct][kh] = *(const s16x8*)&ldsK[row * 64 + (((g + 4 * kh) ^ (row & 7)) * 8)];
      }

    // ---- AC: S[ct] = qw . K^T ----
    f32x4 S[2];
    #pragma unroll
    for (int ct = 0; ct < 2; ++ct) {
      S[ct] = (f32x4){0.f, 0.f, 0.f, 0.f};
      #pragma unroll
      for (int kh = 0; kh < 2; ++kh)
        S[ct] = __builtin_amdgcn_mfma_f32_16x16x32_bf16(qw[kh], kf[ct][kh], S[ct], 0, 0, 0);
    }

    // ---- BD: Btilde = qr . band^T (3 ut tiles from P ring) ----
    const int bbase = 32 * ksub - 16 * qsub + 48;   // wave band offset
    f32x4 bt[3];
    #pragma unroll
    for (int ut = 0; ut < 3; ++ut) {
      const int rel = bbase + 16 * ut + cc;         // [0,127]
      const int rr = rel & 63;
      const short* pp_ = (const short*)(arena + 32768 +
                                        ((rel >= 64) ? sl1 : sl0) * 8192);
      bt[ut] = (f32x4){0.f, 0.f, 0.f, 0.f};
      #pragma unroll
      for (int kh = 0; kh < 2; ++kh) {
        s16x8 pf = *(const s16x8*)&pp_[rr * 64 + (((g + 4 * kh) ^ (rr & 7)) * 8)];
        bt[ut] = __builtin_amdgcn_mfma_f32_16x16x32_bf16(qr[kh], pf, bt[ut], 0, 0, 0);
      }
    }
    // gather: S[ct][r] += Btilde[ii=4g+r][usub=16ct+cc+15-ii] via bpermute
    #pragma unroll
    for (int r = 0; r < 4; ++r) {
      const int usub = cc + 15 - 4 * g - r;            // 0..30
      const int idx = ((lane & 48) | (usub & 15)) << 2;
      const float va = bperm(idx, bt[0][r]);
      const float vb = bperm(idx, bt[1][r]);
      const float vc = bperm(idx, bt[2][r]);
      const bool hi = usub >= 16;
      S[0][r] += hi ? vb : va;
      S[1][r] += hi ? vc : vb;
    }

    // ---- defer-max online softmax (exact) ----
    float mx[4];
    #pragma unroll
    for (int r = 0; r < 4; ++r) mx[r] = fmaxf(S[0][r], S[1][r]);
    const bool need = (mx[0] > mrun[0]) || (mx[1] > mrun[1]) ||
                      (mx[2] > mrun[2]) || (mx[3] > mrun[3]);
    if (__any(need)) {
      #pragma unroll
      for (int msk = 1; msk < 16; msk <<= 1)
        #pragma unroll
        for (int r = 0; r < 4; ++r) mx[r] = fmaxf(mx[r], __shfl_xor(mx[r], msk, 64));
      #pragma unroll
      for (int r = 0; r < 4; ++r) {
        const float mn = fmaxf(mrun[r], mx[r]);
        const float f = __expf(mrun[r] - mn);
        mrun[r] = mn;
        lpart[r] *= f;
        #pragma unroll
        for (int dt = 0; dt < 4; ++dt) O[dt][r] *= f;
      }
    }
    #pragma unroll
    for (int r = 0; r < 4; ++r) {
      S[0][r] = __expf(S[0][r] - mrun[r]);
      S[1][r] = __expf(S[1][r] - mrun[r]);
      lpart[r] += S[0][r] + S[1][r];
    }

    // ---- P to A-fragment layout via wave-private LDS ----
    #pragma unroll
    for (int ct = 0; ct < 2; ++ct)
      #pragma unroll
      for (int r = 0; r < 4; ++r)
        sPm[(4 * g + r) * 40 + 16 * ct + cc] = f2bf(S[ct][r]);

    s16x8 pa = *(const s16x8*)&sPm[cc * 40 + 8 * g];

    // ---- V^T fragments from LDS + PV ----
    #pragma unroll
    for (int dt = 0; dt < 4; ++dt) {
      const int row = 16 * dt + cc;
      s16x8 vf = *(const s16x8*)&ldsV[row * 64 + (((4 * ksub + g) ^ (row & 7)) * 8)];
      O[dt] = __builtin_amdgcn_mfma_f32_16x16x32_bf16(pa, vf, O[dt], 0, 0, 0);
    }

    cur ^= 1;
    const int sln = (sl1 + 1) - (((sl1 + 1) >= 3) ? 3 : 0);
    sl0 = sl1;
    sl1 = sln;
  }
#undef STAGE_KV
#undef STAGE_P

  // ---- final 16-lane sum reduce of lpart ----
  #pragma unroll
  for (int msk = 1; msk < 16; msk <<= 1)
    #pragma unroll
    for (int r = 0; r < 4; ++r) lpart[r] += __shfl_xor(lpart[r], msk, 64);

  __syncthreads();   // all LDS reads done before sO overwrites staging

  // ---- merge pairs (qsub, ksub=0)+(qsub, ksub=1) via LDS ----
  float* sOw = (float*)(arena + wv * 4352);      // [16][68] f32
  #pragma unroll
  for (int dt = 0; dt < 4; ++dt)
    #pragma unroll
    for (int r = 0; r < 4; ++r)
      sOw[(4 * g + r) * 68 + 16 * dt + cc] = O[dt][r];
  float* sML = (float*)(arena + 67584);          // [w][2][16]
  if (cc == 0) {
    #pragma unroll
    for (int r = 0; r < 4; ++r) {
      sML[wv * 32 + (4 * g + r)] = mrun[r];
      sML[wv * 32 + 16 + (4 * g + r)] = lpart[r];
    }
  }
  __syncthreads();

  // 512 threads cover 64 rows x 64 cols, 8 cols/thread
  const int ii = tid >> 3;            // 0..63
  const int ii_l = ii & 15;
  const int w0 = ii >> 4, w1 = w0 + 4;
  const int c0 = (tid & 7) * 8;
  const float m0 = sML[w0 * 32 + ii_l], l0 = sML[w0 * 32 + 16 + ii_l];
  const float m1 = sML[w1 * 32 + ii_l], l1 = sML[w1 * 32 + 16 + ii_l];
  const float M = fmaxf(m0, m1);
  const float f0 = __expf(m0 - M), f1 = __expf(m1 - M);
  const float rinv = 1.0f / (f0 * l0 + f1 * l1);
  const float* sO0 = (const float*)(arena + w0 * 4352);
  const float* sO1 = (const float*)(arena + w1 * 4352);
  s16x8 ov;
  #pragma unroll
  for (int jj = 0; jj < 8; ++jj) {
    const float val = (f0 * sO0[ii_l * 68 + c0 + jj] + f1 * sO1[ii_l * 68 + c0 + jj]) * rinv;
    ov[jj] = f2bf(val);
  }
  *(s16x8*)(ctxb + (size_t)((iq0 + ii) * BB + b) * EE + hoff + c0) = ov;
}

// ---------------------------------------------------------------------------
extern "C" void kernel_launch(void* const* d_in, const int* in_sizes, int n_in,
                              void* d_out, int out_size, void* d_ws, size_t ws_size,
                              hipStream_t stream) {
  const float* x      = (const float*)d_in[0];
  const float* pos    = (const float*)d_in[1];
  const float* in_w   = (const float*)d_in[2];
  const float* in_b   = (const float*)d_in[3];
  const float* pos_w  = (const float*)d_in[4];
  const float* pos_b  = (const float*)d_in[5];
  const float* out_w  = (const float*)d_in[6];
  const float* out_b  = (const float*)d_in[7];
  const float* r_w    = (const float*)d_in[8];
  const float* r_r    = (const float*)d_in[9];
  float* out = (float*)d_out;

  const size_t M1 = 1024 * 1024;
  short* xb    = (short*)d_ws;        // 2M
  short* inwb  = xb    + 2 * M1;      // 3M
  short* posb  = inwb  + 3 * M1;      // 2M (2048 rows, row 2047 zeroed)
  short* poswb = posb  + 2 * M1;      // 1M
  short* outwb = poswb + 1 * M1;      // 1M
  short* qkvb  = outwb + 1 * M1;      // 6M (V third unused; V goes to vTb)
  short* pb    = qkvb  + 6 * M1;      // 2M
  short* ctxb  = pb    + 2 * M1;      // 2M
  short* vTb   = ctxb  + 2 * M1;      // 2M  (B*H*64*1024)

  cvt_all<<<dim3(4608), dim3(256), 0, stream>>>(
      x, in_w, pos, pos_w, out_w, xb, inwb, posb, poswb, outwb);

  // fused qkv-proj + pos-proj (V columns written directly to vT layout)
  gemm_qkv_pos<<<dim3(512), dim3(256), 0, stream>>>(
      xb, inwb, in_b, qkvb, posb, poswb, pos_b, pb, vTb);

  rel_attn_mfma9<<<dim3(512), dim3(512), 0, stream>>>(
      qkvb, pb, vTb, r_w, r_r, ctxb);

  gemm_out<<<dim3(EE / 64, TB / 128), dim3(256), 0, stream>>>(
      ctxb, outwb, out_b, out);
}

// Round 15
// 102.261 us; speedup vs baseline: 1.0832x; 1.0832x over previous
//
#include <hip/hip_runtime.h>
#include <hip/hip_bf16.h>

// Problem constants: T=1024, B=2, E=1024, H=16, D=64, R=2*T-1
#define TT 1024
#define BB 2
#define EE 1024
#define HH 16
#define DD 64
#define RR 2047
#define TB (TT * BB)   // 2048
#define E3 (3 * EE)    // 3072

#define AS1 __attribute__((address_space(1)))
#define AS3 __attribute__((address_space(3)))

typedef __attribute__((ext_vector_type(4))) float f32x4;
typedef __attribute__((ext_vector_type(8))) short s16x8;

static __device__ __forceinline__ short f2bf(float x) {
  unsigned u = __builtin_bit_cast(unsigned, x);
  unsigned r = (u + 0x7FFFu + ((u >> 16) & 1u)) >> 16;
  return (short)r;
}
static __device__ __forceinline__ float bf2f(short x) {
  unsigned u = ((unsigned)(unsigned short)x) << 16;
  return __builtin_bit_cast(float, u);
}
static __device__ __forceinline__ float bperm(int idx, float v) {
  return __builtin_bit_cast(float,
      __builtin_amdgcn_ds_bpermute(idx, __builtin_bit_cast(int, v)));
}
// single-instruction 2^x (v_exp_f32); avoids glibc __exp2f macro collision
static __device__ __forceinline__ float exp2g(float x) {
  return __builtin_amdgcn_exp2f(x);
}

// ---------------------------------------------------------------------------
// Fused fp32 -> bf16 convert for all 5 tensors (one launch).
// ---------------------------------------------------------------------------
__global__ __launch_bounds__(256) void cvt_all(
    const float* __restrict__ x, const float* __restrict__ in_w,
    const float* __restrict__ pos, const float* __restrict__ pos_w,
    const float* __restrict__ out_w,
    short* __restrict__ xb, short* __restrict__ inwb, short* __restrict__ posb,
    short* __restrict__ poswb, short* __restrict__ outwb) {
  const long M1 = 1 << 20;
  long off = (long)(blockIdx.x * 256 + threadIdx.x) * 8;
  const float* src; short* dst; long nsrc;
  if (off < 2 * M1)      { src = x;     dst = xb;    nsrc = 2 * M1; }
  else if (off < 5 * M1) { off -= 2 * M1; src = in_w;  dst = inwb;  nsrc = 3 * M1; }
  else if (off < 7 * M1) { off -= 5 * M1; src = pos;   dst = posb;  nsrc = (long)RR * EE; }
  else if (off < 8 * M1) { off -= 7 * M1; src = pos_w; dst = poswb; nsrc = M1; }
  else                   { off -= 8 * M1; src = out_w; dst = outwb; nsrc = M1; }
  s16x8 o;
  if (off + 8 <= nsrc) {
    f32x4 a = *(const f32x4*)&src[off];
    f32x4 c = *(const f32x4*)&src[off + 4];
    #pragma unroll
    for (int j = 0; j < 4; ++j) { o[j] = f2bf(a[j]); o[4 + j] = f2bf(c[j]); }
  } else {
    #pragma unroll
    for (int j = 0; j < 8; ++j) o[j] = 0;
  }
  *(s16x8*)&dst[off] = o;
}

// ---------------------------------------------------------------------------
// bf16 MFMA GEMM body (m97 structure), BK=64 (half the barrier drains).
//   C[M,N] = A[M,K] @ W[N,K]^T + bias[N]; 256 threads; waves WR x WC.
//   Row = 64 shorts = 8 chunks of 16B; chunk swizzle c8 ^ (row&7), both sides.
//   vtflag: V-part columns written to transposed vT[bh][d][key] layout.
// ---------------------------------------------------------------------------
#define GBK 64

template <int BM, int BN, int WR, int WC, int OUT_BF16>
__device__ __forceinline__ void gemm_body(
    const short* __restrict__ A, const short* __restrict__ W,
    const float* __restrict__ bias, void* __restrict__ Cout,
    int M, int N, int K, int m0, int n0,
    short* __restrict__ vtout, int vtflag) {
  __shared__ __align__(16) short lA[2][BM * GBK];
  __shared__ __align__(16) short lB[2][BN * GBK];
  constexpr int MT = BM / WR / 16;
  constexpr int NT = BN / WC / 16;

  const int tid = threadIdx.x;
  const int lane = tid & 63;
  const int wv = tid >> 6;
  const int g = lane >> 4, cc = lane & 15;
  const int wr = wv / WC, wc = wv % WC;

  f32x4 acc[MT][NT];
  #pragma unroll
  for (int i = 0; i < MT; ++i)
    #pragma unroll
    for (int j = 0; j < NT; ++j) acc[i][j] = (f32x4){0.f, 0.f, 0.f, 0.f};

  auto stage = [&](int kk, int buf) {
    #pragma unroll
    for (int s = 0; s < BM / 32; ++s) {
      int c = s * 256 + tid;
      int row = c >> 3, c8 = c & 7;
      int k8 = c8 ^ (row & 7);
      __builtin_amdgcn_global_load_lds(
          (const AS1 void*)(A + (size_t)(m0 + row) * K + kk + k8 * 8),
          (AS3 void*)&lA[buf][c * 8], 16, 0, 0);
    }
    #pragma unroll
    for (int s = 0; s < BN / 32; ++s) {
      int c = s * 256 + tid;
      int row = c >> 3, c8 = c & 7;
      int k8 = c8 ^ (row & 7);
      __builtin_amdgcn_global_load_lds(
          (const AS1 void*)(W + (size_t)(n0 + row) * K + kk + k8 * 8),
          (AS3 void*)&lB[buf][c * 8], 16, 0, 0);
    }
  };

  int cur = 0;
  const int nt = K / GBK;
  stage(0, 0);

  #pragma unroll 1
  for (int t = 0; t < nt; ++t) {
    __syncthreads();
    if (t + 1 < nt) stage((t + 1) * GBK, cur ^ 1);

    s16x8 af[MT][2], bf[NT][2];
    #pragma unroll
    for (int mt = 0; mt < MT; ++mt) {
      int row = (BM / WR) * wr + 16 * mt + cc;
      #pragma unroll
      for (int kh = 0; kh < 2; ++kh)
        af[mt][kh] = *(const s16x8*)&lA[cur][row * GBK + (((4 * kh + g) ^ (row & 7)) * 8)];
    }
    #pragma unroll
    for (int ntc = 0; ntc < NT; ++ntc) {
      int col = (BN / WC) * wc + 16 * ntc + cc;
      #pragma unroll
      for (int kh = 0; kh < 2; ++kh)
        bf[ntc][kh] = *(const s16x8*)&lB[cur][col * GBK + (((4 * kh + g) ^ (col & 7)) * 8)];
    }
    #pragma unroll
    for (int kh = 0; kh < 2; ++kh)
      #pragma unroll
      for (int mt = 0; mt < MT; ++mt)
        #pragma unroll
        for (int ntc = 0; ntc < NT; ++ntc)
          acc[mt][ntc] = __builtin_amdgcn_mfma_f32_16x16x32_bf16(
              af[mt][kh], bf[ntc][kh], acc[mt][ntc], 0, 0, 0);
    cur ^= 1;
  }

  #pragma unroll
  for (int ntc = 0; ntc < NT; ++ntc) {
    int col = n0 + (BN / WC) * wc + 16 * ntc + cc;
    float bv = bias[col];
    #pragma unroll
    for (int mt = 0; mt < MT; ++mt)
      #pragma unroll
      for (int r = 0; r < 4; ++r) {
        int rowg = m0 + (BM / WR) * wr + 16 * mt + 4 * g + r;
        float val = acc[mt][ntc][r] + bv;
        if (OUT_BF16) {
          if (vtflag) {
            const int cv = col - 2048;
            const int hh = cv >> 6, dd = cv & 63;
            vtout[((size_t)((rowg & 1) * 16 + hh) * 64 + dd) * TT + (rowg >> 1)] =
                f2bf(val);
          } else {
            ((short*)Cout)[(size_t)rowg * N + col] = f2bf(val);
          }
        } else {
          ((float*)Cout)[(size_t)rowg * N + col] = val;
        }
      }
  }
}

// Fused qkv-proj (384 blocks) + pos-proj (128 blocks); V-cols write vT direct.
__global__ __launch_bounds__(256) void gemm_qkv_pos(
    const short* __restrict__ xb, const short* __restrict__ inwb,
    const float* __restrict__ in_b, short* __restrict__ qkvb,
    const short* __restrict__ posb, const short* __restrict__ poswb,
    const float* __restrict__ pos_b, short* __restrict__ pb,
    short* __restrict__ vTb) {
  const int bid = blockIdx.x;
  const short *A, *W; const float* bias; short* C; int N, m0, n0, vtf;
  if (bid < 384) {                // qkv: [2048 x 3072 x 1024]
    A = xb; W = inwb; bias = in_b; C = qkvb; N = E3;
    n0 = (bid % 24) * 128; m0 = (bid / 24) * 128;
    vtf = (n0 >= 2048) ? 1 : 0;   // V columns -> vT layout
  } else {                        // pos: [2048 x 1024 x 1024]
    const int i = bid - 384;
    A = posb; W = poswb; bias = pos_b; C = pb; N = EE;
    n0 = (i % 8) * 128; m0 = (i / 8) * 128;
    vtf = 0;
  }
  gemm_body<128, 128, 2, 2, 1>(A, W, bias, C, TB, N, EE, m0, n0, vTb, vtf);
}

// out-proj: 128x64 tiles -> 256 blocks, fp32 out.
__global__ __launch_bounds__(256) void gemm_out(
    const short* __restrict__ ctxb, const short* __restrict__ outwb,
    const float* __restrict__ out_b, float* __restrict__ out) {
  gemm_body<128, 64, 4, 1, 0>(ctxb, outwb, out_b, out, TB, EE, EE,
                              blockIdx.y * 128, blockIdx.x * 64, nullptr, 0);
}

// ---------------------------------------------------------------------------
// MFMA flash attention — m97-style staged + rolling 3-panel P-ring + exp2.
//   512 blocks (XCD-bijective), 512 thr = 8 waves = (qsub 0..3) x (ksub 0..1).
//   Scores carry a folded scale 0.125*log2(e), so all exponentials are
//   single-instruction exp2 (v_exp_f32 is natively 2^x). Math identical in
//   the scaled domain (max-tracking, lpart, merge all consistent).
// LDS (68608 B): K dbuf @0 (2x8K) | V dbuf @16384 (2x8K) | P ring @32768
//   (3x8K) | sPm @57344 (8x1280) | sML @67584 (1K).
// ---------------------------------------------------------------------------
__global__ __launch_bounds__(512, 4) void rel_attn_mfma9(
    const short* __restrict__ qkvb,  // [TB][3E] bf16 (Q,K parts)
    const short* __restrict__ pb,    // [2048][E] bf16 (row 2047 zeroed)
    const short* __restrict__ vT,    // [BH][64][1024] bf16
    const float* __restrict__ rwb,   // [H*D]
    const float* __restrict__ rrb,   // [H*D]
    short* __restrict__ ctxb) {      // [TB][E] bf16
  __shared__ __align__(16) char arena[68608];

  const int tid = threadIdx.x;
  const int wv = tid >> 6;
  const int qsub = wv & 3, ksub = wv >> 2;
  const int lane = tid & 63;
  const int g = lane >> 4, cc = lane & 15;

  const int bid = blockIdx.x;
  const int bh = (bid & 7) * 4 + (bid >> 7);   // [0,32)
  const int qx = (bid >> 3) & 15;              // [0,16)
  const int iq0 = qx * 64;
  const int b = bh >> 4, h = bh & 15;
  const int hoff = h * DD;
  const int n0p = 15 - qx;                     // absolute panel idx at step 0

  short* sPm = (short*)(arena + 57344 + wv * 1280);    // [16][40]

  // ---- Q fragments: q row = iq0 + 16*qsub + cc; scale folds 1/8 * log2e ----
  const float qscale = 0.125f * 1.44269504088896f;
  s16x8 qw[2], qr[2];
  #pragma unroll
  for (int kh = 0; kh < 2; ++kh) {
    const int d0 = 32 * kh + 8 * g;
    const short* qp = qkvb + (size_t)((iq0 + 16 * qsub + cc) * BB + b) * E3 + hoff + d0;
    const float* rw = rwb + hoff + d0;
    const float* rr = rrb + hoff + d0;
    s16x8 qv = *(const s16x8*)qp;
    #pragma unroll
    for (int j = 0; j < 8; ++j) {
      float q = bf2f(qv[j]);
      qw[kh][j] = f2bf((q + rw[j]) * qscale);
      qr[kh][j] = f2bf((q + rr[j]) * qscale);
    }
  }

  f32x4 O[4];
  #pragma unroll
  for (int dt = 0; dt < 4; ++dt) O[dt] = (f32x4){0.f, 0.f, 0.f, 0.f};
  float mrun[4], lpart[4];
  #pragma unroll
  for (int r = 0; r < 4; ++r) { mrun[r] = -1e30f; lpart[r] = 0.f; }

#define STAGE_KV(t_, buf_)                                                     \
  {                                                                            \
    const int j0s = (t_) * 64;                                                 \
    const int row = tid >> 3, c8 = tid & 7;                                    \
    const int swz = (c8 ^ (row & 7)) * 8;                                      \
    __builtin_amdgcn_global_load_lds(                                          \
        (const AS1 void*)(qkvb + (size_t)((j0s + row) * BB + b) * E3 + EE + hoff + swz), \
        (AS3 void*)(arena + (buf_) * 8192 + tid * 16), 16, 0, 0);              \
    __builtin_amdgcn_global_load_lds(                                          \
        (const AS1 void*)(vT + (size_t)(bh * DD + row) * TT + j0s + swz),      \
        (AS3 void*)(arena + 16384 + (buf_) * 8192 + tid * 16), 16, 0, 0);      \
  }
#define STAGE_P(p_)                                                            \
  {                                                                            \
    const int row = tid >> 3, c8 = tid & 7;                                    \
    const int swz = (c8 ^ (row & 7)) * 8;                                      \
    __builtin_amdgcn_global_load_lds(                                          \
        (const AS1 void*)(pb + (size_t)((p_) * 64 + row) * EE + hoff + swz),   \
        (AS3 void*)(arena + 32768 + ((p_) % 3) * 8192 + tid * 16), 16, 0, 0);  \
  }

  int cur = 0;
  int sl0 = n0p % 3, sl1 = (n0p + 1) % 3;
  STAGE_KV(0, 0);
  STAGE_P(n0p);
  STAGE_P(n0p + 1);

  #pragma unroll 1
  for (int t = 0; t < 16; ++t) {
    __syncthreads();   // stage(t) landed; buf[cur^1] + ring slot free
    if (t + 1 < 16) {
      STAGE_KV(t + 1, cur ^ 1);
      STAGE_P(n0p + t + 2);
    }

    short* ldsK = (short*)(arena + cur * 8192);           // [64 keys][64 d]
    short* ldsV = (short*)(arena + 16384 + cur * 8192);   // [64 d][64 keys]

    // ---- K fragments ----
    s16x8 kf[2][2];
    #pragma unroll
    for (int ct = 0; ct < 2; ++ct)
      #pragma unroll
      for (int kh = 0; kh < 2; ++kh) {
        const int row = 32 * ksub + 16 * ct + cc;
        kf[ct][kh] = *(const s16x8*)&ldsK[row * 64 + (((g + 4 * kh) ^ (row & 7)) * 8)];
      }

    // ---- AC: S[ct] = qw . K^T ----
    f32x4 S[2];
    #pragma unroll
    for (int ct = 0; ct < 2; ++ct) {
      S[ct] = (f32x4){0.f, 0.f, 0.f, 0.f};
      #pragma unroll
      for (int kh = 0; kh < 2; ++kh)
        S[ct] = __builtin_amdgcn_mfma_f32_16x16x32_bf16(qw[kh], kf[ct][kh], S[ct], 0, 0, 0);
    }

    // ---- BD: Btilde = qr . band^T (3 ut tiles from P ring) ----
    const int bbase = 32 * ksub - 16 * qsub + 48;   // wave band offset
    f32x4 bt[3];
    #pragma unroll
    for (int ut = 0; ut < 3; ++ut) {
      const int rel = bbase + 16 * ut + cc;         // [0,127]
      const int rr = rel & 63;
      const short* pp_ = (const short*)(arena + 32768 +
                                        ((rel >= 64) ? sl1 : sl0) * 8192);
      bt[ut] = (f32x4){0.f, 0.f, 0.f, 0.f};
      #pragma unroll
      for (int kh = 0; kh < 2; ++kh) {
        s16x8 pf = *(const s16x8*)&pp_[rr * 64 + (((g + 4 * kh) ^ (rr & 7)) * 8)];
        bt[ut] = __builtin_amdgcn_mfma_f32_16x16x32_bf16(qr[kh], pf, bt[ut], 0, 0, 0);
      }
    }
    // gather: S[ct][r] += Btilde[ii=4g+r][usub=16ct+cc+15-ii] via bpermute
    #pragma unroll
    for (int r = 0; r < 4; ++r) {
      const int usub = cc + 15 - 4 * g - r;            // 0..30
      const int idx = ((lane & 48) | (usub & 15)) << 2;
      const float va = bperm(idx, bt[0][r]);
      const float vb = bperm(idx, bt[1][r]);
      const float vc = bperm(idx, bt[2][r]);
      const bool hi = usub >= 16;
      S[0][r] += hi ? vb : va;
      S[1][r] += hi ? vc : vb;
    }

    // ---- defer-max online softmax (exact, base-2 domain) ----
    float mx[4];
    #pragma unroll
    for (int r = 0; r < 4; ++r) mx[r] = fmaxf(S[0][r], S[1][r]);
    const bool need = (mx[0] > mrun[0]) || (mx[1] > mrun[1]) ||
                      (mx[2] > mrun[2]) || (mx[3] > mrun[3]);
    if (__any(need)) {
      #pragma unroll
      for (int msk = 1; msk < 16; msk <<= 1)
        #pragma unroll
        for (int r = 0; r < 4; ++r) mx[r] = fmaxf(mx[r], __shfl_xor(mx[r], msk, 64));
      #pragma unroll
      for (int r = 0; r < 4; ++r) {
        const float mn = fmaxf(mrun[r], mx[r]);
        const float f = exp2g(mrun[r] - mn);
        mrun[r] = mn;
        lpart[r] *= f;
        #pragma unroll
        for (int dt = 0; dt < 4; ++dt) O[dt][r] *= f;
      }
    }
    #pragma unroll
    for (int r = 0; r < 4; ++r) {
      S[0][r] = exp2g(S[0][r] - mrun[r]);
      S[1][r] = exp2g(S[1][r] - mrun[r]);
      lpart[r] += S[0][r] + S[1][r];
    }

    // ---- P to A-fragment layout via wave-private LDS ----
    #pragma unroll
    for (int ct = 0; ct < 2; ++ct)
      #pragma unroll
      for (int r = 0; r < 4; ++r)
        sPm[(4 * g + r) * 40 + 16 * ct + cc] = f2bf(S[ct][r]);

    s16x8 pa = *(const s16x8*)&sPm[cc * 40 + 8 * g];

    // ---- V^T fragments from LDS + PV ----
    #pragma unroll
    for (int dt = 0; dt < 4; ++dt) {
      const int row = 16 * dt + cc;
      s16x8 vf = *(const s16x8*)&ldsV[row * 64 + (((4 * ksub + g) ^ (row & 7)) * 8)];
      O[dt] = __builtin_amdgcn_mfma_f32_16x16x32_bf16(pa, vf, O[dt], 0, 0, 0);
    }

    cur ^= 1;
    const int sln = (sl1 + 1) - (((sl1 + 1) >= 3) ? 3 : 0);
    sl0 = sl1;
    sl1 = sln;
  }
#undef STAGE_KV
#undef STAGE_P

  // ---- final 16-lane sum reduce of lpart ----
  #pragma unroll
  for (int msk = 1; msk < 16; msk <<= 1)
    #pragma unroll
    for (int r = 0; r < 4; ++r) lpart[r] += __shfl_xor(lpart[r], msk, 64);

  __syncthreads();   // all LDS reads done before sO overwrites staging

  // ---- merge pairs (qsub, ksub=0)+(qsub, ksub=1) via LDS ----
  float* sOw = (float*)(arena + wv * 4352);      // [16][68] f32
  #pragma unroll
  for (int dt = 0; dt < 4; ++dt)
    #pragma unroll
    for (int r = 0; r < 4; ++r)
      sOw[(4 * g + r) * 68 + 16 * dt + cc] = O[dt][r];
  float* sML = (float*)(arena + 67584);          // [w][2][16]
  if (cc == 0) {
    #pragma unroll
    for (int r = 0; r < 4; ++r) {
      sML[wv * 32 + (4 * g + r)] = mrun[r];
      sML[wv * 32 + 16 + (4 * g + r)] = lpart[r];
    }
  }
  __syncthreads();

  // 512 threads cover 64 rows x 64 cols, 8 cols/thread
  const int ii = tid >> 3;            // 0..63
  const int ii_l = ii & 15;
  const int w0 = ii >> 4, w1 = w0 + 4;
  const int c0 = (tid & 7) * 8;
  const float m0 = sML[w0 * 32 + ii_l], l0 = sML[w0 * 32 + 16 + ii_l];
  const float m1 = sML[w1 * 32 + ii_l], l1 = sML[w1 * 32 + 16 + ii_l];
  const float M = fmaxf(m0, m1);
  const float f0 = exp2g(m0 - M), f1 = exp2g(m1 - M);
  const float rinv = 1.0f / (f0 * l0 + f1 * l1);
  const float* sO0 = (const float*)(arena + w0 * 4352);
  const float* sO1 = (const float*)(arena + w1 * 4352);
  s16x8 ov;
  #pragma unroll
  for (int jj = 0; jj < 8; ++jj) {
    const float val = (f0 * sO0[ii_l * 68 + c0 + jj] + f1 * sO1[ii_l * 68 + c0 + jj]) * rinv;
    ov[jj] = f2bf(val);
  }
  *(s16x8*)(ctxb + (size_t)((iq0 + ii) * BB + b) * EE + hoff + c0) = ov;
}

// ---------------------------------------------------------------------------
extern "C" void kernel_launch(void* const* d_in, const int* in_sizes, int n_in,
                              void* d_out, int out_size, void* d_ws, size_t ws_size,
                              hipStream_t stream) {
  const float* x      = (const float*)d_in[0];
  const float* pos    = (const float*)d_in[1];
  const float* in_w   = (const float*)d_in[2];
  const float* in_b   = (const float*)d_in[3];
  const float* pos_w  = (const float*)d_in[4];
  const float* pos_b  = (const float*)d_in[5];
  const float* out_w  = (const float*)d_in[6];
  const float* out_b  = (const float*)d_in[7];
  const float* r_w    = (const float*)d_in[8];
  const float* r_r    = (const float*)d_in[9];
  float* out = (float*)d_out;

  const size_t M1 = 1024 * 1024;
  short* xb    = (short*)d_ws;        // 2M
  short* inwb  = xb    + 2 * M1;      // 3M
  short* posb  = inwb  + 3 * M1;      // 2M (2048 rows, row 2047 zeroed)
  short* poswb = posb  + 2 * M1;      // 1M
  short* outwb = poswb + 1 * M1;      // 1M
  short* qkvb  = outwb + 1 * M1;      // 6M (V third unused; V goes to vTb)
  short* pb    = qkvb  + 6 * M1;      // 2M
  short* ctxb  = pb    + 2 * M1;      // 2M
  short* vTb   = ctxb  + 2 * M1;      // 2M  (B*H*64*1024)

  cvt_all<<<dim3(4608), dim3(256), 0, stream>>>(
      x, in_w, pos, pos_w, out_w, xb, inwb, posb, poswb, outwb);

  gemm_qkv_pos<<<dim3(512), dim3(256), 0, stream>>>(
      xb, inwb, in_b, qkvb, posb, poswb, pos_b, pb, vTb);

  rel_attn_mfma9<<<dim3(512), dim3(512), 0, stream>>>(
      qkvb, pb, vTb, r_w, r_r, ctxb);

  gemm_out<<<dim3(EE / 64, TB / 128), dim3(256), 0, stream>>>(
      ctxb, outwb, out_b, out);
}